// Round 15
// baseline (138.618 us; speedup 1.0000x reference)
//
#include <hip/hip_runtime.h>

// GCN layer: out = D^-1/2 (A + I) D^-1/2 (x @ kernel) + bias
// N=100000, E=1600000, F=U=64, fp32 in/out; h2 staged as bf16.
// Pipeline: fixed-capacity bucket scatter (128-node buckets, CAP=mean+10sig),
// single-pass LDS fine sort (in-place), GEMM pre-scaled by dis, pull.
// Occupancy fix (r15): SB=7 + TILE=2048 -> 782 blocks (~3/CU) for both
// bscatter and fine (391 blocks = 1.5/CU was latency-bound).
// Config notes (measured): pull body = round-10 form (51.6us floor) — any
// ILP restructuring (unroll-4, dual-node, batch-8) regresses it.

typedef unsigned long long u64;
#define FILL 1.0f
#define SB 7
#define BKN 128
#define TILE 2048
#define TSH 11
#define CAP 2528

__device__ inline unsigned bf16rne(float f) {
    unsigned u = __float_as_uint(f);
    return (u + 0x7FFFu + ((u >> 16) & 1u)) >> 16;
}
__device__ inline unsigned pack2(float lo, float hi) {
    return bf16rne(lo) | (bf16rne(hi) << 16);
}
__device__ inline float unlo(unsigned g) { return __uint_as_float(g << 16); }
__device__ inline float unhi(unsigned g) { return __uint_as_float(g & 0xFFFF0000u); }

// ---------------- phase 0: bucket cursors = fixed region bases ----------------

__global__ void k_init(int* __restrict__ bcur, int NB) {
    int i = blockIdx.x * blockDim.x + threadIdx.x;
    if (i < NB) bcur[i] = i * CAP;
}

// ---------------- phase 1: tile-reserved bucket scatter (two-pass) ----------
// record: w(63..32) | row_local(30..24, 7 bits) | col(23..0)

__global__ __launch_bounds__(256) void k_bscatter(const int* __restrict__ row,
                                                  const int* __restrict__ col,
                                                  const float* __restrict__ w,
                                                  int* __restrict__ bcur,
                                                  u64* __restrict__ eA, int E, int NB) {
    __shared__ int cnt[1024];
    __shared__ int ofs[1024];
    int nt = (E + TILE - 1) >> TSH;
    for (int tile = blockIdx.x; tile < nt; tile += gridDim.x) {
        int base = tile << TSH;
        int lim = E - base; if (lim > TILE) lim = TILE;
        for (int i = threadIdx.x; i < NB; i += 256) cnt[i] = 0;
        __syncthreads();
        for (int i = threadIdx.x; i < lim; i += 256)
            atomicAdd(&cnt[row[base + i] >> SB], 1);
        __syncthreads();
        for (int i = threadIdx.x; i < NB; i += 256) {
            int c = cnt[i];
            ofs[i] = c ? atomicAdd(&bcur[i], c) : 0;
            cnt[i] = 0;
        }
        __syncthreads();
        for (int i = threadIdx.x; i < lim; i += 256) {
            int e = base + i;
            int r = row[e];
            int b = r >> SB;
            int pos = ofs[b] + atomicAdd(&cnt[b], 1);
            if (pos < (b + 1) * CAP)   // 10-sigma guard, never triggers
                eA[pos] = ((u64)__float_as_uint(w[e]) << 32)
                        | ((u64)(unsigned)(r & (BKN - 1)) << 24)
                        | (u64)(unsigned)col[e];
        }
        __syncthreads();
    }
}

// ------- phase 2: single-pass LDS fine sort (in-place) + start/end + dis -----

__global__ __launch_bounds__(256) void k_fine(const int* __restrict__ bcur,
                                              u64* __restrict__ eA,
                                              int* __restrict__ start,
                                              int* __restrict__ end,
                                              float* __restrict__ dis, int N) {
    __shared__ u64 lrec[CAP];                 // 20224 B
    __shared__ int ncnt[BKN];
    __shared__ float degs[BKN];
    __shared__ int sa[BKN], sb2[BKN];
    int b = blockIdx.x;
    int s = b * CAP;
    int cnt = bcur[b] - s;
    if (cnt > CAP) cnt = CAP;
    int t = threadIdx.x;
    if (t < BKN) { ncnt[t] = 0; degs[t] = 0.f; }
    __syncthreads();
    // load + count in one pass
    for (int i = t; i < cnt; i += 256) {
        u64 p = eA[s + i];
        lrec[i] = p;
        int rl = (int)((p >> 24) & (BKN - 1));
        atomicAdd(&ncnt[rl], 1);
        atomicAdd(&degs[rl], __uint_as_float((unsigned)(p >> 32)));
    }
    __syncthreads();
    int c = 0;
    if (t < BKN) { c = ncnt[t]; sa[t] = c; }
    __syncthreads();
    int *src = sa, *dst = sb2;
    for (int o = 1; o < BKN; o <<= 1) {
        if (t < BKN) {
            int v = src[t];
            if (t >= o) v += src[t - o];
            dst[t] = v;
        }
        __syncthreads();
        int* tm = src; src = dst; dst = tm;
    }
    if (t < BKN) {
        int excl = src[t] - c;
        int node = (b << SB) + t;
        if (node < N) {
            start[node] = s + excl;
            end[node]   = s + excl + c;
            float d = FILL + degs[t];
            dis[node] = (d > 0.f) ? rsqrtf(fmaxf(d, 1e-12f)) : 0.f;
        }
        ncnt[t] = excl;          // reuse as bucket-relative cursor
    }
    __syncthreads();
    for (int i = t; i < cnt; i += 256) {
        u64 p = lrec[i];
        int rl = (int)((p >> 24) & (BKN - 1));
        int pos = atomicAdd(&ncnt[rl], 1);
        eA[s + pos] = p & 0xFFFFFFFF00FFFFFFULL;
    }
}

// ---------------- h2b = bf16( dis[r] * (x @ kernel) ) ----------------

__global__ __launch_bounds__(256) void k_gemm(const float* __restrict__ x,
                                              const float* __restrict__ kern,
                                              const float* __restrict__ dis,
                                              unsigned* __restrict__ h2b, int n) {
    __shared__ __align__(16) float ks[64 * 64];
    __shared__ __align__(16) float xs[64 * 68];
    int t = threadIdx.x;

    const float4* k4g = (const float4*)kern;
    float4* ks4 = (float4*)ks;
    #pragma unroll
    for (int i = 0; i < 4; ++i) ks4[t + i * 256] = k4g[t + i * 256];

    int r0 = blockIdx.x * 64;
    #pragma unroll
    for (int i = 0; i < 4; ++i) {
        int idx = t + i * 256;
        int rr = idx >> 4;
        int c4 = (idx & 15) << 2;
        int gr = r0 + rr;
        float4 v = make_float4(0.f, 0.f, 0.f, 0.f);
        if (gr < n) v = *(const float4*)(x + (size_t)gr * 64 + c4);
        *(float4*)(xs + rr * 68 + c4) = v;
    }
    __syncthreads();

    int rg = t >> 4;
    int ug = t & 15;
    float4 acc[4];
    #pragma unroll
    for (int r = 0; r < 4; ++r) acc[r] = make_float4(0.f, 0.f, 0.f, 0.f);

    #pragma unroll 2
    for (int kk = 0; kk < 16; ++kk) {
        float4 wv0 = *(const float4*)(ks + (kk * 4 + 0) * 64 + ug * 4);
        float4 wv1 = *(const float4*)(ks + (kk * 4 + 1) * 64 + ug * 4);
        float4 wv2 = *(const float4*)(ks + (kk * 4 + 2) * 64 + ug * 4);
        float4 wv3 = *(const float4*)(ks + (kk * 4 + 3) * 64 + ug * 4);
        #pragma unroll
        for (int r = 0; r < 4; ++r) {
            float4 xv = *(const float4*)(xs + (rg * 4 + r) * 68 + kk * 4);
            acc[r].x = fmaf(xv.x, wv0.x, acc[r].x);
            acc[r].y = fmaf(xv.x, wv0.y, acc[r].y);
            acc[r].z = fmaf(xv.x, wv0.z, acc[r].z);
            acc[r].w = fmaf(xv.x, wv0.w, acc[r].w);
            acc[r].x = fmaf(xv.y, wv1.x, acc[r].x);
            acc[r].y = fmaf(xv.y, wv1.y, acc[r].y);
            acc[r].z = fmaf(xv.y, wv1.z, acc[r].z);
            acc[r].w = fmaf(xv.y, wv1.w, acc[r].w);
            acc[r].x = fmaf(xv.z, wv2.x, acc[r].x);
            acc[r].y = fmaf(xv.z, wv2.y, acc[r].y);
            acc[r].z = fmaf(xv.z, wv2.z, acc[r].z);
            acc[r].w = fmaf(xv.z, wv2.w, acc[r].w);
            acc[r].x = fmaf(xv.w, wv3.x, acc[r].x);
            acc[r].y = fmaf(xv.w, wv3.y, acc[r].y);
            acc[r].z = fmaf(xv.w, wv3.z, acc[r].z);
            acc[r].w = fmaf(xv.w, wv3.w, acc[r].w);
        }
    }

    #pragma unroll
    for (int r = 0; r < 4; ++r) {
        int gr = r0 + rg * 4 + r;
        if (gr < n) {
            float d = dis[gr];
            uint2 uu;
            uu.x = pack2(d * acc[r].x, d * acc[r].y);
            uu.y = pack2(d * acc[r].z, d * acc[r].w);
            *(uint2*)(h2b + (size_t)gr * 32 + ug * 2) = uu;
        }
    }
}

// -------- phase 4: pull, wave per node, 4 edge slots x 16 lanes x uint2 ------

__global__ __launch_bounds__(256) void k_pull(const int* __restrict__ start,
                                              const int* __restrict__ end,
                                              const u64* __restrict__ edges,
                                              const unsigned* __restrict__ h2b,
                                              const float* __restrict__ dis,
                                              const float* __restrict__ bias,
                                              float* __restrict__ out, int N) {
    int node = (blockIdx.x << 2) + (threadIdx.x >> 6);
    int lane = threadIdx.x & 63;
    if (node >= N) return;
    int s = start[node], e1 = end[node];
    int slot = lane >> 4;   // 0..3: which edge of each quad
    int uw   = lane & 15;   // uint2 word pair -> units 4uw..4uw+3
    float a0 = 0.f, a1 = 0.f, a2 = 0.f, a3 = 0.f;
    #pragma unroll 2
    for (int j = s + slot; j < e1; j += 4) {
        u64 p = edges[j];                 // broadcast load (same addr per 16 lanes)
        unsigned c = (unsigned)p & 0xFFFFFFu;
        float v = __uint_as_float((unsigned)(p >> 32));
        uint2 g = *(const uint2*)(h2b + ((size_t)c << 5) + (uw << 1));
        a0 = fmaf(v, unlo(g.x), a0);
        a1 = fmaf(v, unhi(g.x), a1);
        a2 = fmaf(v, unlo(g.y), a2);
        a3 = fmaf(v, unhi(g.y), a3);
    }
    a0 += __shfl_xor(a0, 16); a0 += __shfl_xor(a0, 32);
    a1 += __shfl_xor(a1, 16); a1 += __shfl_xor(a1, 32);
    a2 += __shfl_xor(a2, 16); a2 += __shfl_xor(a2, 32);
    a3 += __shfl_xor(a3, 16); a3 += __shfl_xor(a3, 32);
    if (slot == 0) {
        float di = dis[node];
        uint2 gs = *(const uint2*)(h2b + ((size_t)node << 5) + (uw << 1));
        float4 bv = *(const float4*)(bias + 4 * uw);
        float4 o;
        o.x = di * (a0 + FILL * unlo(gs.x)) + bv.x;
        o.y = di * (a1 + FILL * unhi(gs.x)) + bv.y;
        o.z = di * (a2 + FILL * unlo(gs.y)) + bv.z;
        o.w = di * (a3 + FILL * unhi(gs.y)) + bv.w;
        *(float4*)(out + ((size_t)node << 6) + 4 * uw) = o;
    }
}

// ---------------- fallback (atomic scatter) ----------------

__global__ void k_fb_deg_init(float* __restrict__ deg, int n) {
    int i = blockIdx.x * blockDim.x + threadIdx.x;
    if (i < n) deg[i] = FILL;
}
__global__ void k_fb_deg_edges(const int* __restrict__ row, const float* __restrict__ w,
                               float* __restrict__ deg, int E) {
    int e = blockIdx.x * blockDim.x + threadIdx.x;
    if (e < E) atomicAdd(&deg[row[e]], w[e]);
}
__global__ void k_fb_dis(const float* __restrict__ deg, float* __restrict__ dis, int n) {
    int i = blockIdx.x * blockDim.x + threadIdx.x;
    if (i < n) {
        float d = deg[i];
        dis[i] = (d > 0.f) ? rsqrtf(fmaxf(d, 1e-12f)) : 0.f;
    }
}
__global__ void k_fb_outinit(const unsigned* __restrict__ h2b, const float* __restrict__ dis,
                             const float* __restrict__ bias, float* __restrict__ out, int n) {
    int t = blockIdx.x * blockDim.x + threadIdx.x;
    if (t < n * 64) {
        int i = t >> 6, u = t & 63;
        unsigned g = h2b[(size_t)i * 32 + (u >> 1)];
        float hv = (u & 1) ? unhi(g) : unlo(g);
        out[t] = FILL * dis[i] * hv + bias[u];
    }
}
__global__ __launch_bounds__(256) void k_fb_scatter(const int* __restrict__ row,
                                                    const int* __restrict__ col,
                                                    const float* __restrict__ w,
                                                    const float* __restrict__ dis,
                                                    const unsigned* __restrict__ h2b,
                                                    float* __restrict__ out, int E) {
    long long t = (long long)blockIdx.x * blockDim.x + threadIdx.x;
    int e = (int)(t >> 4);
    int j = (int)(t & 15);
    if (e < E) {
        int r = row[e], c = col[e];
        float nw = dis[r] * w[e];
        uint2 g2 = *(const uint2*)(h2b + (size_t)c * 32 + 2 * j);
        float* op = out + (long long)r * 64 + j * 4;
        atomicAdd(op + 0, unlo(g2.x) * nw);
        atomicAdd(op + 1, unhi(g2.x) * nw);
        atomicAdd(op + 2, unlo(g2.y) * nw);
        atomicAdd(op + 3, unhi(g2.y) * nw);
    }
}

// ---------------- launch ----------------

extern "C" void kernel_launch(void* const* d_in, const int* in_sizes, int n_in,
                              void* d_out, int out_size, void* d_ws, size_t ws_size,
                              hipStream_t stream) {
    const float* x    = (const float*)d_in[0];
    const int*   ei   = (const int*)d_in[1];
    const float* ew   = (const float*)d_in[2];
    const float* kern = (const float*)d_in[3];
    const float* bias = (const float*)d_in[4];
    float* out = (float*)d_out;

    int N = in_sizes[0] / 64;
    int E = in_sizes[1] / 2;
    const int* row = ei;
    const int* col = ei + E;

    const int B = 256;
    int NB = (N + BKN - 1) >> SB;

    // capacity check: CAP must exceed mean bucket fill by >= 8 sigma
    double meanB = (double)E / NB;
    bool capOK = (double)CAP >= meanB + 8.0 * sqrt(meanB) + 32.0;

    size_t need = (size_t)NB * CAP * 8        // eA (fixed-capacity regions)
                + (size_t)N * 128             // h2b (bf16 pairs)
                + (size_t)N * 4               // dis
                + (size_t)N * 4               // start
                + (size_t)N * 4               // end
                + (size_t)NB * 4;             // bcur

    if (ws_size >= need && capOK && NB <= 1024 && N <= (1 << 24)) {
        char* p = (char*)d_ws;
        u64*      eA    = (u64*)p;         p += (size_t)NB * CAP * 8;
        unsigned* h2b   = (unsigned*)p;    p += (size_t)N * 128;
        float*    dis   = (float*)p;       p += (size_t)N * 4;
        int*      start = (int*)p;         p += (size_t)N * 4;
        int*      end   = (int*)p;         p += (size_t)N * 4;
        int*      bcur  = (int*)p;

        int nt = (E + TILE - 1) >> TSH;
        k_init<<<(NB + B - 1) / B, B, 0, stream>>>(bcur, NB);
        k_bscatter<<<nt, B, 0, stream>>>(row, col, ew, bcur, eA, E, NB);
        k_fine<<<NB, B, 0, stream>>>(bcur, eA, start, end, dis, N);
        k_gemm<<<(N + 63) / 64, B, 0, stream>>>(x, kern, dis, h2b, N);
        k_pull<<<(N + 3) / 4, B, 0, stream>>>(start, end, eA, h2b, dis, bias, out, N);
    } else {
        char* p = (char*)d_ws;
        unsigned* h2b = (unsigned*)p;  p += (size_t)N * 128;
        float*    deg = (float*)p;     p += (size_t)N * 4;
        float*    dis = (float*)p;

        k_fb_deg_init<<<(N + B - 1) / B, B, 0, stream>>>(deg, N);
        k_fb_deg_edges<<<(E + B - 1) / B, B, 0, stream>>>(row, ew, deg, E);
        k_fb_dis<<<(N + B - 1) / B, B, 0, stream>>>(deg, dis, N);
        k_gemm<<<(N + 63) / 64, B, 0, stream>>>(x, kern, dis, h2b, N);
        k_fb_outinit<<<((long long)N * 64 + B - 1) / B, B, 0, stream>>>(h2b, dis, bias, out, N);
        long long st = (long long)E * 16;
        k_fb_scatter<<<(st + B - 1) / B, B, 0, stream>>>(row, col, ew, dis, h2b, out, E);
    }
}

// Round 16
// 132.640 us; speedup vs baseline: 1.0451x; 1.0451x over previous
//
#include <hip/hip_runtime.h>

// GCN layer: out = D^-1/2 (A + I) D^-1/2 (x @ kernel) + bias
// N=100000, E=1600000, F=U=64, fp32 in/out; h2 staged as bf16.
// Pipeline: fixed-capacity bucket scatter (256-node buckets, CAP=mean+10sig,
// bucket-relative cursors, no init kernel), single-pass LDS fine sort
// (in-place), GEMM pre-scaled by dis, pull (wave/node, 4 slots x 16 lanes).
// Config notes (measured): SB=8 + TILE>=4096 required — SB=7/TILE=2048
// fragments eA write runs (52us bscatter). Pull body = round-10 form
// (51.6us floor); all ILP restructurings of it regressed.

typedef unsigned long long u64;
#define FILL 1.0f
#define SB 8
#define BKN 256
#define TILE 8192
#define TSH 13
#define CAP 4736

__device__ inline unsigned bf16rne(float f) {
    unsigned u = __float_as_uint(f);
    return (u + 0x7FFFu + ((u >> 16) & 1u)) >> 16;
}
__device__ inline unsigned pack2(float lo, float hi) {
    return bf16rne(lo) | (bf16rne(hi) << 16);
}
__device__ inline float unlo(unsigned g) { return __uint_as_float(g << 16); }
__device__ inline float unhi(unsigned g) { return __uint_as_float(g & 0xFFFF0000u); }

// ---------------- phase 1: tile-reserved bucket scatter (two-pass) ----------
// record: w(63..32) | row_local(31..24) | col(23..0)
// bcnt[] zeroed by memset; cursors are bucket-relative, region base = b*CAP.

__global__ __launch_bounds__(256) void k_bscatter(const int* __restrict__ row,
                                                  const int* __restrict__ col,
                                                  const float* __restrict__ w,
                                                  int* __restrict__ bcnt,
                                                  u64* __restrict__ eA, int E, int NB) {
    __shared__ int cnt[512];
    __shared__ int ofs[512];
    int nt = (E + TILE - 1) >> TSH;
    for (int tile = blockIdx.x; tile < nt; tile += gridDim.x) {
        int base = tile << TSH;
        int lim = E - base; if (lim > TILE) lim = TILE;
        for (int i = threadIdx.x; i < NB; i += 256) cnt[i] = 0;
        __syncthreads();
        for (int i = threadIdx.x; i < lim; i += 256)
            atomicAdd(&cnt[row[base + i] >> SB], 1);
        __syncthreads();
        for (int i = threadIdx.x; i < NB; i += 256) {
            int c = cnt[i];
            ofs[i] = c ? atomicAdd(&bcnt[i], c) : 0;
            cnt[i] = 0;
        }
        __syncthreads();
        for (int i = threadIdx.x; i < lim; i += 256) {
            int e = base + i;
            int r = row[e];
            int b = r >> SB;
            int pos = ofs[b] + atomicAdd(&cnt[b], 1);
            if (pos < CAP)   // 10-sigma guard, never triggers
                eA[(size_t)b * CAP + pos] =
                      ((u64)__float_as_uint(w[e]) << 32)
                    | ((u64)(unsigned)(r & (BKN - 1)) << 24)
                    | (u64)(unsigned)col[e];
        }
        __syncthreads();
    }
}

// ------- phase 2: single-pass LDS fine sort (in-place) + start/end + dis -----

__global__ __launch_bounds__(256) void k_fine(const int* __restrict__ bcnt,
                                              u64* __restrict__ eA,
                                              int* __restrict__ start,
                                              int* __restrict__ end,
                                              float* __restrict__ dis, int N) {
    __shared__ u64 lrec[CAP];                 // 37888 B
    __shared__ int ncnt[256];
    __shared__ float degs[256];
    __shared__ int sa[256], sb2[256];
    int b = blockIdx.x;
    int s = b * CAP;
    int cnt = bcnt[b];
    if (cnt > CAP) cnt = CAP;
    int t = threadIdx.x;
    ncnt[t] = 0;
    degs[t] = 0.f;
    __syncthreads();
    // load + count in one pass
    for (int i = t; i < cnt; i += 256) {
        u64 p = eA[s + i];
        lrec[i] = p;
        int rl = (int)((p >> 24) & 0xFF);
        atomicAdd(&ncnt[rl], 1);
        atomicAdd(&degs[rl], __uint_as_float((unsigned)(p >> 32)));
    }
    __syncthreads();
    int c = ncnt[t];
    sa[t] = c;
    __syncthreads();
    int *src = sa, *dst = sb2;
    for (int o = 1; o < 256; o <<= 1) {
        int v = src[t];
        if (t >= o) v += src[t - o];
        dst[t] = v;
        __syncthreads();
        int* tm = src; src = dst; dst = tm;
    }
    int excl = src[t] - c;
    int node = (b << SB) + t;
    if (node < N) {
        start[node] = s + excl;
        end[node]   = s + excl + c;
        float d = FILL + degs[t];
        dis[node] = (d > 0.f) ? rsqrtf(fmaxf(d, 1e-12f)) : 0.f;
    }
    ncnt[t] = excl;          // reuse as bucket-relative cursor
    __syncthreads();
    for (int i = t; i < cnt; i += 256) {
        u64 p = lrec[i];
        int rl = (int)((p >> 24) & 0xFF);
        int pos = atomicAdd(&ncnt[rl], 1);
        eA[s + pos] = p & 0xFFFFFFFF00FFFFFFULL;
    }
}

// ---------------- h2b = bf16( dis[r] * (x @ kernel) ) ----------------

__global__ __launch_bounds__(256) void k_gemm(const float* __restrict__ x,
                                              const float* __restrict__ kern,
                                              const float* __restrict__ dis,
                                              unsigned* __restrict__ h2b, int n) {
    __shared__ __align__(16) float ks[64 * 64];
    __shared__ __align__(16) float xs[64 * 68];
    int t = threadIdx.x;

    const float4* k4g = (const float4*)kern;
    float4* ks4 = (float4*)ks;
    #pragma unroll
    for (int i = 0; i < 4; ++i) ks4[t + i * 256] = k4g[t + i * 256];

    int r0 = blockIdx.x * 64;
    #pragma unroll
    for (int i = 0; i < 4; ++i) {
        int idx = t + i * 256;
        int rr = idx >> 4;
        int c4 = (idx & 15) << 2;
        int gr = r0 + rr;
        float4 v = make_float4(0.f, 0.f, 0.f, 0.f);
        if (gr < n) v = *(const float4*)(x + (size_t)gr * 64 + c4);
        *(float4*)(xs + rr * 68 + c4) = v;
    }
    __syncthreads();

    int rg = t >> 4;
    int ug = t & 15;
    float4 acc[4];
    #pragma unroll
    for (int r = 0; r < 4; ++r) acc[r] = make_float4(0.f, 0.f, 0.f, 0.f);

    #pragma unroll 2
    for (int kk = 0; kk < 16; ++kk) {
        float4 wv0 = *(const float4*)(ks + (kk * 4 + 0) * 64 + ug * 4);
        float4 wv1 = *(const float4*)(ks + (kk * 4 + 1) * 64 + ug * 4);
        float4 wv2 = *(const float4*)(ks + (kk * 4 + 2) * 64 + ug * 4);
        float4 wv3 = *(const float4*)(ks + (kk * 4 + 3) * 64 + ug * 4);
        #pragma unroll
        for (int r = 0; r < 4; ++r) {
            float4 xv = *(const float4*)(xs + (rg * 4 + r) * 68 + kk * 4);
            acc[r].x = fmaf(xv.x, wv0.x, acc[r].x);
            acc[r].y = fmaf(xv.x, wv0.y, acc[r].y);
            acc[r].z = fmaf(xv.x, wv0.z, acc[r].z);
            acc[r].w = fmaf(xv.x, wv0.w, acc[r].w);
            acc[r].x = fmaf(xv.y, wv1.x, acc[r].x);
            acc[r].y = fmaf(xv.y, wv1.y, acc[r].y);
            acc[r].z = fmaf(xv.y, wv1.z, acc[r].z);
            acc[r].w = fmaf(xv.y, wv1.w, acc[r].w);
            acc[r].x = fmaf(xv.z, wv2.x, acc[r].x);
            acc[r].y = fmaf(xv.z, wv2.y, acc[r].y);
            acc[r].z = fmaf(xv.z, wv2.z, acc[r].z);
            acc[r].w = fmaf(xv.z, wv2.w, acc[r].w);
            acc[r].x = fmaf(xv.w, wv3.x, acc[r].x);
            acc[r].y = fmaf(xv.w, wv3.y, acc[r].y);
            acc[r].z = fmaf(xv.w, wv3.z, acc[r].z);
            acc[r].w = fmaf(xv.w, wv3.w, acc[r].w);
        }
    }

    #pragma unroll
    for (int r = 0; r < 4; ++r) {
        int gr = r0 + rg * 4 + r;
        if (gr < n) {
            float d = dis[gr];
            uint2 uu;
            uu.x = pack2(d * acc[r].x, d * acc[r].y);
            uu.y = pack2(d * acc[r].z, d * acc[r].w);
            *(uint2*)(h2b + (size_t)gr * 32 + ug * 2) = uu;
        }
    }
}

// -------- phase 4: pull, wave per node, 4 edge slots x 16 lanes x uint2 ------

__global__ __launch_bounds__(256) void k_pull(const int* __restrict__ start,
                                              const int* __restrict__ end,
                                              const u64* __restrict__ edges,
                                              const unsigned* __restrict__ h2b,
                                              const float* __restrict__ dis,
                                              const float* __restrict__ bias,
                                              float* __restrict__ out, int N) {
    int node = (blockIdx.x << 2) + (threadIdx.x >> 6);
    int lane = threadIdx.x & 63;
    if (node >= N) return;
    int s = start[node], e1 = end[node];
    int slot = lane >> 4;   // 0..3: which edge of each quad
    int uw   = lane & 15;   // uint2 word pair -> units 4uw..4uw+3
    float a0 = 0.f, a1 = 0.f, a2 = 0.f, a3 = 0.f;
    #pragma unroll 2
    for (int j = s + slot; j < e1; j += 4) {
        u64 p = edges[j];                 // broadcast load (same addr per 16 lanes)
        unsigned c = (unsigned)p & 0xFFFFFFu;
        float v = __uint_as_float((unsigned)(p >> 32));
        uint2 g = *(const uint2*)(h2b + ((size_t)c << 5) + (uw << 1));
        a0 = fmaf(v, unlo(g.x), a0);
        a1 = fmaf(v, unhi(g.x), a1);
        a2 = fmaf(v, unlo(g.y), a2);
        a3 = fmaf(v, unhi(g.y), a3);
    }
    a0 += __shfl_xor(a0, 16); a0 += __shfl_xor(a0, 32);
    a1 += __shfl_xor(a1, 16); a1 += __shfl_xor(a1, 32);
    a2 += __shfl_xor(a2, 16); a2 += __shfl_xor(a2, 32);
    a3 += __shfl_xor(a3, 16); a3 += __shfl_xor(a3, 32);
    if (slot == 0) {
        float di = dis[node];
        uint2 gs = *(const uint2*)(h2b + ((size_t)node << 5) + (uw << 1));
        float4 bv = *(const float4*)(bias + 4 * uw);
        float4 o;
        o.x = di * (a0 + FILL * unlo(gs.x)) + bv.x;
        o.y = di * (a1 + FILL * unhi(gs.x)) + bv.y;
        o.z = di * (a2 + FILL * unlo(gs.y)) + bv.z;
        o.w = di * (a3 + FILL * unhi(gs.y)) + bv.w;
        *(float4*)(out + ((size_t)node << 6) + 4 * uw) = o;
    }
}

// ---------------- fallback (atomic scatter) ----------------

__global__ void k_fb_deg_init(float* __restrict__ deg, int n) {
    int i = blockIdx.x * blockDim.x + threadIdx.x;
    if (i < n) deg[i] = FILL;
}
__global__ void k_fb_deg_edges(const int* __restrict__ row, const float* __restrict__ w,
                               float* __restrict__ deg, int E) {
    int e = blockIdx.x * blockDim.x + threadIdx.x;
    if (e < E) atomicAdd(&deg[row[e]], w[e]);
}
__global__ void k_fb_dis(const float* __restrict__ deg, float* __restrict__ dis, int n) {
    int i = blockIdx.x * blockDim.x + threadIdx.x;
    if (i < n) {
        float d = deg[i];
        dis[i] = (d > 0.f) ? rsqrtf(fmaxf(d, 1e-12f)) : 0.f;
    }
}
__global__ void k_fb_outinit(const unsigned* __restrict__ h2b, const float* __restrict__ dis,
                             const float* __restrict__ bias, float* __restrict__ out, int n) {
    int t = blockIdx.x * blockDim.x + threadIdx.x;
    if (t < n * 64) {
        int i = t >> 6, u = t & 63;
        unsigned g = h2b[(size_t)i * 32 + (u >> 1)];
        float hv = (u & 1) ? unhi(g) : unlo(g);
        out[t] = FILL * dis[i] * hv + bias[u];
    }
}
__global__ __launch_bounds__(256) void k_fb_scatter(const int* __restrict__ row,
                                                    const int* __restrict__ col,
                                                    const float* __restrict__ w,
                                                    const float* __restrict__ dis,
                                                    const unsigned* __restrict__ h2b,
                                                    float* __restrict__ out, int E) {
    long long t = (long long)blockIdx.x * blockDim.x + threadIdx.x;
    int e = (int)(t >> 4);
    int j = (int)(t & 15);
    if (e < E) {
        int r = row[e], c = col[e];
        float nw = dis[r] * w[e];
        uint2 g2 = *(const uint2*)(h2b + (size_t)c * 32 + 2 * j);
        float* op = out + (long long)r * 64 + j * 4;
        atomicAdd(op + 0, unlo(g2.x) * nw);
        atomicAdd(op + 1, unhi(g2.x) * nw);
        atomicAdd(op + 2, unlo(g2.y) * nw);
        atomicAdd(op + 3, unhi(g2.y) * nw);
    }
}

// ---------------- launch ----------------

extern "C" void kernel_launch(void* const* d_in, const int* in_sizes, int n_in,
                              void* d_out, int out_size, void* d_ws, size_t ws_size,
                              hipStream_t stream) {
    const float* x    = (const float*)d_in[0];
    const int*   ei   = (const int*)d_in[1];
    const float* ew   = (const float*)d_in[2];
    const float* kern = (const float*)d_in[3];
    const float* bias = (const float*)d_in[4];
    float* out = (float*)d_out;

    int N = in_sizes[0] / 64;
    int E = in_sizes[1] / 2;
    const int* row = ei;
    const int* col = ei + E;

    const int B = 256;
    int NB = (N + BKN - 1) >> SB;

    // capacity check: CAP must exceed mean bucket fill by >= 8 sigma
    double meanB = (double)E / NB;
    bool capOK = (double)CAP >= meanB + 8.0 * sqrt(meanB) + 32.0;

    size_t need = (size_t)NB * CAP * 8        // eA (fixed-capacity regions)
                + (size_t)N * 128             // h2b (bf16 pairs)
                + (size_t)N * 4               // dis
                + (size_t)N * 4               // start
                + (size_t)N * 4               // end
                + (size_t)NB * 4;             // bcnt

    if (ws_size >= need && capOK && NB <= 512 && N <= (1 << 24)) {
        char* p = (char*)d_ws;
        u64*      eA    = (u64*)p;         p += (size_t)NB * CAP * 8;
        unsigned* h2b   = (unsigned*)p;    p += (size_t)N * 128;
        float*    dis   = (float*)p;       p += (size_t)N * 4;
        int*      start = (int*)p;         p += (size_t)N * 4;
        int*      end   = (int*)p;         p += (size_t)N * 4;
        int*      bcnt  = (int*)p;

        int nt = (E + TILE - 1) >> TSH;
        hipMemsetAsync(bcnt, 0, (size_t)NB * 4, stream);
        k_bscatter<<<nt, B, 0, stream>>>(row, col, ew, bcnt, eA, E, NB);
        k_fine<<<NB, B, 0, stream>>>(bcnt, eA, start, end, dis, N);
        k_gemm<<<(N + 63) / 64, B, 0, stream>>>(x, kern, dis, h2b, N);
        k_pull<<<(N + 3) / 4, B, 0, stream>>>(start, end, eA, h2b, dis, bias, out, N);
    } else {
        char* p = (char*)d_ws;
        unsigned* h2b = (unsigned*)p;  p += (size_t)N * 128;
        float*    deg = (float*)p;     p += (size_t)N * 4;
        float*    dis = (float*)p;

        k_fb_deg_init<<<(N + B - 1) / B, B, 0, stream>>>(deg, N);
        k_fb_deg_edges<<<(E + B - 1) / B, B, 0, stream>>>(row, ew, deg, E);
        k_fb_dis<<<(N + B - 1) / B, B, 0, stream>>>(deg, dis, N);
        k_gemm<<<(N + 63) / 64, B, 0, stream>>>(x, kern, dis, h2b, N);
        k_fb_outinit<<<((long long)N * 64 + B - 1) / B, B, 0, stream>>>(h2b, dis, bias, out, N);
        long long st = (long long)E * 16;
        k_fb_scatter<<<(st + B - 1) / B, B, 0, stream>>>(row, col, ew, dis, h2b, out, E);
    }
}

// Round 17
// 129.107 us; speedup vs baseline: 1.0737x; 1.0274x over previous
//
#include <hip/hip_runtime.h>

// GCN layer: out = D^-1/2 (A + I) D^-1/2 (x @ kernel) + bias
// N=100000, E=1600000, F=U=64, fp32 in/out; h2 staged as bf16.
// Pipeline: fixed-capacity bucket scatter (256-node buckets, CAP=mean+10sig),
// fused fine-sort+GEMM per bucket (LDS overlay: lrec reused as ks/xs),
// pull (wave/node, 4 slots x 16 lanes).
// Config notes (measured): TILE=4096 optimal (2048 fragments writes: 52us;
// 8192 starves CUs: +8us). Pull body = round-10 form (51.6us floor); all
// ILP restructurings regressed it. SB=8 required (SB=7 fragments runs).

typedef unsigned long long u64;
#define FILL 1.0f
#define SB 8
#define BKN 256
#define TILE 4096
#define TSH 12
#define CAP 4736

__device__ inline unsigned bf16rne(float f) {
    unsigned u = __float_as_uint(f);
    return (u + 0x7FFFu + ((u >> 16) & 1u)) >> 16;
}
__device__ inline unsigned pack2(float lo, float hi) {
    return bf16rne(lo) | (bf16rne(hi) << 16);
}
__device__ inline float unlo(unsigned g) { return __uint_as_float(g << 16); }
__device__ inline float unhi(unsigned g) { return __uint_as_float(g & 0xFFFF0000u); }

// ---------------- phase 1: tile-reserved bucket scatter (two-pass) ----------
// record: w(63..32) | row_local(31..24) | col(23..0)
// bcnt[] zeroed by memset; cursors bucket-relative, region base = b*CAP.

__global__ __launch_bounds__(256) void k_bscatter(const int* __restrict__ row,
                                                  const int* __restrict__ col,
                                                  const float* __restrict__ w,
                                                  int* __restrict__ bcnt,
                                                  u64* __restrict__ eA, int E, int NB) {
    __shared__ int cnt[512];
    __shared__ int ofs[512];
    int nt = (E + TILE - 1) >> TSH;
    for (int tile = blockIdx.x; tile < nt; tile += gridDim.x) {
        int base = tile << TSH;
        int lim = E - base; if (lim > TILE) lim = TILE;
        for (int i = threadIdx.x; i < NB; i += 256) cnt[i] = 0;
        __syncthreads();
        for (int i = threadIdx.x; i < lim; i += 256)
            atomicAdd(&cnt[row[base + i] >> SB], 1);
        __syncthreads();
        for (int i = threadIdx.x; i < NB; i += 256) {
            int c = cnt[i];
            ofs[i] = c ? atomicAdd(&bcnt[i], c) : 0;
            cnt[i] = 0;
        }
        __syncthreads();
        for (int i = threadIdx.x; i < lim; i += 256) {
            int e = base + i;
            int r = row[e];
            int b = r >> SB;
            int pos = ofs[b] + atomicAdd(&cnt[b], 1);
            if (pos < CAP)   // 10-sigma guard, never triggers
                eA[(size_t)b * CAP + pos] =
                      ((u64)__float_as_uint(w[e]) << 32)
                    | ((u64)(unsigned)(r & (BKN - 1)) << 24)
                    | (u64)(unsigned)col[e];
        }
        __syncthreads();
    }
}

// --- phase 2 (fused): fine sort (in-place) + start/end/dis + GEMM for bucket -
// LDS overlay: lrec[CAP] (37.9 KB) reused as ks[64*64] + xs[64*68] after sort.

__global__ __launch_bounds__(256) void k_finegemm(const int* __restrict__ bcnt,
                                                  u64* __restrict__ eA,
                                                  int* __restrict__ start,
                                                  int* __restrict__ end,
                                                  float* __restrict__ dis,
                                                  const float* __restrict__ x,
                                                  const float* __restrict__ kern,
                                                  unsigned* __restrict__ h2b, int N) {
    __shared__ __align__(16) u64 lrec[CAP];   // 37888 B, overlaid by ks+xs later
    __shared__ int ncnt[256];
    __shared__ float degs[256];
    __shared__ float disl[256];
    __shared__ int sa[256], sb2[256];
    int b = blockIdx.x;
    int s = b * CAP;
    int cnt = bcnt[b];
    if (cnt > CAP) cnt = CAP;
    int t = threadIdx.x;
    ncnt[t] = 0;
    degs[t] = 0.f;
    __syncthreads();
    // ---- fine sort: load + count in one pass ----
    for (int i = t; i < cnt; i += 256) {
        u64 p = eA[s + i];
        lrec[i] = p;
        int rl = (int)((p >> 24) & 0xFF);
        atomicAdd(&ncnt[rl], 1);
        atomicAdd(&degs[rl], __uint_as_float((unsigned)(p >> 32)));
    }
    __syncthreads();
    int c = ncnt[t];
    sa[t] = c;
    __syncthreads();
    int *src = sa, *dst = sb2;
    for (int o = 1; o < 256; o <<= 1) {
        int v = src[t];
        if (t >= o) v += src[t - o];
        dst[t] = v;
        __syncthreads();
        int* tm = src; src = dst; dst = tm;
    }
    {
        int excl = src[t] - c;
        int node = (b << SB) + t;
        float d = FILL + degs[t];
        float di = (d > 0.f) ? rsqrtf(fmaxf(d, 1e-12f)) : 0.f;
        disl[t] = di;
        if (node < N) {
            start[node] = s + excl;
            end[node]   = s + excl + c;
            dis[node]   = di;
        }
        ncnt[t] = excl;          // reuse as bucket-relative cursor
    }
    __syncthreads();
    for (int i = t; i < cnt; i += 256) {
        u64 p = lrec[i];
        int rl = (int)((p >> 24) & 0xFF);
        int pos = atomicAdd(&ncnt[rl], 1);
        eA[s + pos] = p & 0xFFFFFFFF00FFFFFFULL;
    }
    __syncthreads();             // lrec dead from here: overlay ks+xs

    // ---- GEMM for this bucket's 256 nodes, 4 chunks of 64 rows ----
    float* ks = (float*)lrec;                  // 4096 floats (16 KB)
    float* xs = ((float*)lrec) + 4096;         // 4352 floats (17 KB)

    const float4* k4g = (const float4*)kern;
    float4* ks4 = (float4*)ks;
    #pragma unroll
    for (int i = 0; i < 4; ++i) ks4[t + i * 256] = k4g[t + i * 256];

    int rg = t >> 4;
    int ug = t & 15;

    for (int ch = 0; ch < 4; ++ch) {
        int r0 = (b << SB) + (ch << 6);
        __syncthreads();         // prev chunk compute done before xs overwrite
        #pragma unroll
        for (int i = 0; i < 4; ++i) {
            int idx = t + i * 256;
            int rr = idx >> 4;
            int c4 = (idx & 15) << 2;
            int gr = r0 + rr;
            float4 v = make_float4(0.f, 0.f, 0.f, 0.f);
            if (gr < N) v = *(const float4*)(x + (size_t)gr * 64 + c4);
            *(float4*)(xs + rr * 68 + c4) = v;
        }
        __syncthreads();

        float4 acc[4];
        #pragma unroll
        for (int r = 0; r < 4; ++r) acc[r] = make_float4(0.f, 0.f, 0.f, 0.f);

        #pragma unroll 2
        for (int kk = 0; kk < 16; ++kk) {
            float4 wv0 = *(const float4*)(ks + (kk * 4 + 0) * 64 + ug * 4);
            float4 wv1 = *(const float4*)(ks + (kk * 4 + 1) * 64 + ug * 4);
            float4 wv2 = *(const float4*)(ks + (kk * 4 + 2) * 64 + ug * 4);
            float4 wv3 = *(const float4*)(ks + (kk * 4 + 3) * 64 + ug * 4);
            #pragma unroll
            for (int r = 0; r < 4; ++r) {
                float4 xv = *(const float4*)(xs + (rg * 4 + r) * 68 + kk * 4);
                acc[r].x = fmaf(xv.x, wv0.x, acc[r].x);
                acc[r].y = fmaf(xv.x, wv0.y, acc[r].y);
                acc[r].z = fmaf(xv.x, wv0.z, acc[r].z);
                acc[r].w = fmaf(xv.x, wv0.w, acc[r].w);
                acc[r].x = fmaf(xv.y, wv1.x, acc[r].x);
                acc[r].y = fmaf(xv.y, wv1.y, acc[r].y);
                acc[r].z = fmaf(xv.y, wv1.z, acc[r].z);
                acc[r].w = fmaf(xv.y, wv1.w, acc[r].w);
                acc[r].x = fmaf(xv.z, wv2.x, acc[r].x);
                acc[r].y = fmaf(xv.z, wv2.y, acc[r].y);
                acc[r].z = fmaf(xv.z, wv2.z, acc[r].z);
                acc[r].w = fmaf(xv.z, wv2.w, acc[r].w);
                acc[r].x = fmaf(xv.w, wv3.x, acc[r].x);
                acc[r].y = fmaf(xv.w, wv3.y, acc[r].y);
                acc[r].z = fmaf(xv.w, wv3.z, acc[r].z);
                acc[r].w = fmaf(xv.w, wv3.w, acc[r].w);
            }
        }

        #pragma unroll
        for (int r = 0; r < 4; ++r) {
            int rl = (ch << 6) + rg * 4 + r;
            int gr = (b << SB) + rl;
            if (gr < N) {
                float d = disl[rl];
                uint2 uu;
                uu.x = pack2(d * acc[r].x, d * acc[r].y);
                uu.y = pack2(d * acc[r].z, d * acc[r].w);
                *(uint2*)(h2b + (size_t)gr * 32 + ug * 2) = uu;
            }
        }
    }
}

// -------- phase 3: pull, wave per node, 4 edge slots x 16 lanes x uint2 ------

__global__ __launch_bounds__(256) void k_pull(const int* __restrict__ start,
                                              const int* __restrict__ end,
                                              const u64* __restrict__ edges,
                                              const unsigned* __restrict__ h2b,
                                              const float* __restrict__ dis,
                                              const float* __restrict__ bias,
                                              float* __restrict__ out, int N) {
    int node = (blockIdx.x << 2) + (threadIdx.x >> 6);
    int lane = threadIdx.x & 63;
    if (node >= N) return;
    int s = start[node], e1 = end[node];
    int slot = lane >> 4;   // 0..3: which edge of each quad
    int uw   = lane & 15;   // uint2 word pair -> units 4uw..4uw+3
    float a0 = 0.f, a1 = 0.f, a2 = 0.f, a3 = 0.f;
    #pragma unroll 2
    for (int j = s + slot; j < e1; j += 4) {
        u64 p = edges[j];                 // broadcast load (same addr per 16 lanes)
        unsigned c = (unsigned)p & 0xFFFFFFu;
        float v = __uint_as_float((unsigned)(p >> 32));
        uint2 g = *(const uint2*)(h2b + ((size_t)c << 5) + (uw << 1));
        a0 = fmaf(v, unlo(g.x), a0);
        a1 = fmaf(v, unhi(g.x), a1);
        a2 = fmaf(v, unlo(g.y), a2);
        a3 = fmaf(v, unhi(g.y), a3);
    }
    a0 += __shfl_xor(a0, 16); a0 += __shfl_xor(a0, 32);
    a1 += __shfl_xor(a1, 16); a1 += __shfl_xor(a1, 32);
    a2 += __shfl_xor(a2, 16); a2 += __shfl_xor(a2, 32);
    a3 += __shfl_xor(a3, 16); a3 += __shfl_xor(a3, 32);
    if (slot == 0) {
        float di = dis[node];
        uint2 gs = *(const uint2*)(h2b + ((size_t)node << 5) + (uw << 1));
        float4 bv = *(const float4*)(bias + 4 * uw);
        float4 o;
        o.x = di * (a0 + FILL * unlo(gs.x)) + bv.x;
        o.y = di * (a1 + FILL * unhi(gs.x)) + bv.y;
        o.z = di * (a2 + FILL * unlo(gs.y)) + bv.z;
        o.w = di * (a3 + FILL * unhi(gs.y)) + bv.w;
        *(float4*)(out + ((size_t)node << 6) + 4 * uw) = o;
    }
}

// ---------------- fallback (atomic scatter) ----------------

__global__ __launch_bounds__(256) void k_fb_gemm(const float* __restrict__ x,
                                                 const float* __restrict__ kern,
                                                 const float* __restrict__ dis,
                                                 unsigned* __restrict__ h2b, int n) {
    __shared__ __align__(16) float ks[64 * 64];
    __shared__ __align__(16) float xs[64 * 68];
    int t = threadIdx.x;
    const float4* k4g = (const float4*)kern;
    float4* ks4 = (float4*)ks;
    #pragma unroll
    for (int i = 0; i < 4; ++i) ks4[t + i * 256] = k4g[t + i * 256];
    int r0 = blockIdx.x * 64;
    #pragma unroll
    for (int i = 0; i < 4; ++i) {
        int idx = t + i * 256;
        int rr = idx >> 4;
        int c4 = (idx & 15) << 2;
        int gr = r0 + rr;
        float4 v = make_float4(0.f, 0.f, 0.f, 0.f);
        if (gr < n) v = *(const float4*)(x + (size_t)gr * 64 + c4);
        *(float4*)(xs + rr * 68 + c4) = v;
    }
    __syncthreads();
    int rg = t >> 4, ug = t & 15;
    float4 acc[4];
    #pragma unroll
    for (int r = 0; r < 4; ++r) acc[r] = make_float4(0.f, 0.f, 0.f, 0.f);
    #pragma unroll 2
    for (int kk = 0; kk < 16; ++kk) {
        float4 wv0 = *(const float4*)(ks + (kk * 4 + 0) * 64 + ug * 4);
        float4 wv1 = *(const float4*)(ks + (kk * 4 + 1) * 64 + ug * 4);
        float4 wv2 = *(const float4*)(ks + (kk * 4 + 2) * 64 + ug * 4);
        float4 wv3 = *(const float4*)(ks + (kk * 4 + 3) * 64 + ug * 4);
        #pragma unroll
        for (int r = 0; r < 4; ++r) {
            float4 xv = *(const float4*)(xs + (rg * 4 + r) * 68 + kk * 4);
            acc[r].x = fmaf(xv.x, wv0.x, acc[r].x);
            acc[r].y = fmaf(xv.x, wv0.y, acc[r].y);
            acc[r].z = fmaf(xv.x, wv0.z, acc[r].z);
            acc[r].w = fmaf(xv.x, wv0.w, acc[r].w);
            acc[r].x = fmaf(xv.y, wv1.x, acc[r].x);
            acc[r].y = fmaf(xv.y, wv1.y, acc[r].y);
            acc[r].z = fmaf(xv.y, wv1.z, acc[r].z);
            acc[r].w = fmaf(xv.y, wv1.w, acc[r].w);
            acc[r].x = fmaf(xv.z, wv2.x, acc[r].x);
            acc[r].y = fmaf(xv.z, wv2.y, acc[r].y);
            acc[r].z = fmaf(xv.z, wv2.z, acc[r].z);
            acc[r].w = fmaf(xv.z, wv2.w, acc[r].w);
            acc[r].x = fmaf(xv.w, wv3.x, acc[r].x);
            acc[r].y = fmaf(xv.w, wv3.y, acc[r].y);
            acc[r].z = fmaf(xv.w, wv3.z, acc[r].z);
            acc[r].w = fmaf(xv.w, wv3.w, acc[r].w);
        }
    }
    #pragma unroll
    for (int r = 0; r < 4; ++r) {
        int gr = r0 + rg * 4 + r;
        if (gr < n) {
            float d = dis[gr];
            uint2 uu;
            uu.x = pack2(d * acc[r].x, d * acc[r].y);
            uu.y = pack2(d * acc[r].z, d * acc[r].w);
            *(uint2*)(h2b + (size_t)gr * 32 + ug * 2) = uu;
        }
    }
}

__global__ void k_fb_deg_init(float* __restrict__ deg, int n) {
    int i = blockIdx.x * blockDim.x + threadIdx.x;
    if (i < n) deg[i] = FILL;
}
__global__ void k_fb_deg_edges(const int* __restrict__ row, const float* __restrict__ w,
                               float* __restrict__ deg, int E) {
    int e = blockIdx.x * blockDim.x + threadIdx.x;
    if (e < E) atomicAdd(&deg[row[e]], w[e]);
}
__global__ void k_fb_dis(const float* __restrict__ deg, float* __restrict__ dis, int n) {
    int i = blockIdx.x * blockDim.x + threadIdx.x;
    if (i < n) {
        float d = deg[i];
        dis[i] = (d > 0.f) ? rsqrtf(fmaxf(d, 1e-12f)) : 0.f;
    }
}
__global__ void k_fb_outinit(const unsigned* __restrict__ h2b, const float* __restrict__ dis,
                             const float* __restrict__ bias, float* __restrict__ out, int n) {
    int t = blockIdx.x * blockDim.x + threadIdx.x;
    if (t < n * 64) {
        int i = t >> 6, u = t & 63;
        unsigned g = h2b[(size_t)i * 32 + (u >> 1)];
        float hv = (u & 1) ? unhi(g) : unlo(g);
        out[t] = FILL * dis[i] * hv + bias[u];
    }
}
__global__ __launch_bounds__(256) void k_fb_scatter(const int* __restrict__ row,
                                                    const int* __restrict__ col,
                                                    const float* __restrict__ w,
                                                    const float* __restrict__ dis,
                                                    const unsigned* __restrict__ h2b,
                                                    float* __restrict__ out, int E) {
    long long t = (long long)blockIdx.x * blockDim.x + threadIdx.x;
    int e = (int)(t >> 4);
    int j = (int)(t & 15);
    if (e < E) {
        int r = row[e], c = col[e];
        float nw = dis[r] * w[e];
        uint2 g2 = *(const uint2*)(h2b + (size_t)c * 32 + 2 * j);
        float* op = out + (long long)r * 64 + j * 4;
        atomicAdd(op + 0, unlo(g2.x) * nw);
        atomicAdd(op + 1, unhi(g2.x) * nw);
        atomicAdd(op + 2, unlo(g2.y) * nw);
        atomicAdd(op + 3, unhi(g2.y) * nw);
    }
}

// ---------------- launch ----------------

extern "C" void kernel_launch(void* const* d_in, const int* in_sizes, int n_in,
                              void* d_out, int out_size, void* d_ws, size_t ws_size,
                              hipStream_t stream) {
    const float* x    = (const float*)d_in[0];
    const int*   ei   = (const int*)d_in[1];
    const float* ew   = (const float*)d_in[2];
    const float* kern = (const float*)d_in[3];
    const float* bias = (const float*)d_in[4];
    float* out = (float*)d_out;

    int N = in_sizes[0] / 64;
    int E = in_sizes[1] / 2;
    const int* row = ei;
    const int* col = ei + E;

    const int B = 256;
    int NB = (N + BKN - 1) >> SB;

    // capacity check: CAP must exceed mean bucket fill by >= 8 sigma
    double meanB = (double)E / NB;
    bool capOK = (double)CAP >= meanB + 8.0 * sqrt(meanB) + 32.0;

    size_t need = (size_t)NB * CAP * 8        // eA (fixed-capacity regions)
                + (size_t)N * 128             // h2b (bf16 pairs)
                + (size_t)N * 4               // dis
                + (size_t)N * 4               // start
                + (size_t)N * 4               // end
                + (size_t)NB * 4;             // bcnt

    if (ws_size >= need && capOK && NB <= 512 && N <= (1 << 24)) {
        char* p = (char*)d_ws;
        u64*      eA    = (u64*)p;         p += (size_t)NB * CAP * 8;
        unsigned* h2b   = (unsigned*)p;    p += (size_t)N * 128;
        float*    dis   = (float*)p;       p += (size_t)N * 4;
        int*      start = (int*)p;         p += (size_t)N * 4;
        int*      end   = (int*)p;         p += (size_t)N * 4;
        int*      bcnt  = (int*)p;

        int nt = (E + TILE - 1) >> TSH;
        hipMemsetAsync(bcnt, 0, (size_t)NB * 4, stream);
        k_bscatter<<<nt, B, 0, stream>>>(row, col, ew, bcnt, eA, E, NB);
        k_finegemm<<<NB, B, 0, stream>>>(bcnt, eA, start, end, dis, x, kern, h2b, N);
        k_pull<<<(N + 3) / 4, B, 0, stream>>>(start, end, eA, h2b, dis, bias, out, N);
    } else {
        char* p = (char*)d_ws;
        unsigned* h2b = (unsigned*)p;  p += (size_t)N * 128;
        float*    deg = (float*)p;     p += (size_t)N * 4;
        float*    dis = (float*)p;

        k_fb_deg_init<<<(N + B - 1) / B, B, 0, stream>>>(deg, N);
        k_fb_deg_edges<<<(E + B - 1) / B, B, 0, stream>>>(row, ew, deg, E);
        k_fb_dis<<<(N + B - 1) / B, B, 0, stream>>>(deg, dis, N);
        k_fb_gemm<<<(N + 63) / 64, B, 0, stream>>>(x, kern, dis, h2b, N);
        k_fb_outinit<<<((long long)N * 64 + B - 1) / B, B, 0, stream>>>(h2b, dis, bias, out, N);
        long long st = (long long)E * 16;
        k_fb_scatter<<<(st + B - 1) / B, B, 0, stream>>>(row, col, ew, dis, h2b, out, E);
    }
}

// Round 18
// 125.045 us; speedup vs baseline: 1.1085x; 1.0325x over previous
//
#include <hip/hip_runtime.h>

// GCN layer: out = D^-1/2 (A + I) D^-1/2 (x @ kernel) + bias
// N=100000, E=1600000, F=U=64, fp32 in/out; h2 staged as bf16.
// Pipeline: fixed-capacity bucket scatter (CAP = mean+10sigma, no histogram/
// scan needed), single-pass LDS fine sort (in-place, start/end arrays),
// GEMM rows pre-scaled by dis, pull (wave per node, 4 edge slots x 16 lanes).
// == Round-14 configuration: the measured optimum of this pipeline ==
// Bracketed axes (all measured): TILE 2048/4096/8192 -> 4096 best;
// SB 7/8 -> 8 best; pull ILP variants (unroll-4, dual-node, batch-8) all
// regress the 51.6us floor; fine 256thr > 512thr; fine+gemm fusion regresses;
// fused histscan regresses; LDS-tile pull (no sort) regresses.

typedef unsigned long long u64;
#define FILL 1.0f
#define SB 8
#define BKN 256
#define TILE 4096
#define TSH 12
#define CAP 4736

__device__ inline unsigned bf16rne(float f) {
    unsigned u = __float_as_uint(f);
    return (u + 0x7FFFu + ((u >> 16) & 1u)) >> 16;
}
__device__ inline unsigned pack2(float lo, float hi) {
    return bf16rne(lo) | (bf16rne(hi) << 16);
}
__device__ inline float unlo(unsigned g) { return __uint_as_float(g << 16); }
__device__ inline float unhi(unsigned g) { return __uint_as_float(g & 0xFFFF0000u); }

// ---------------- phase 0: bucket cursors = fixed region bases ----------------

__global__ void k_init(int* __restrict__ bcur, int NB) {
    int i = blockIdx.x * blockDim.x + threadIdx.x;
    if (i < NB) bcur[i] = i * CAP;
}

// ---------------- phase 1: tile-reserved bucket scatter (two-pass) ----------
// record: w(63..32) | row_local(31..24) | col(23..0)

__global__ __launch_bounds__(256) void k_bscatter(const int* __restrict__ row,
                                                  const int* __restrict__ col,
                                                  const float* __restrict__ w,
                                                  int* __restrict__ bcur,
                                                  u64* __restrict__ eA, int E, int NB) {
    __shared__ int cnt[512];
    __shared__ int ofs[512];
    int nt = (E + TILE - 1) >> TSH;
    for (int tile = blockIdx.x; tile < nt; tile += gridDim.x) {
        int base = tile << TSH;
        int lim = E - base; if (lim > TILE) lim = TILE;
        for (int i = threadIdx.x; i < NB; i += 256) cnt[i] = 0;
        __syncthreads();
        for (int i = threadIdx.x; i < lim; i += 256)
            atomicAdd(&cnt[row[base + i] >> SB], 1);
        __syncthreads();
        for (int i = threadIdx.x; i < NB; i += 256) {
            int c = cnt[i];
            ofs[i] = c ? atomicAdd(&bcur[i], c) : 0;
            cnt[i] = 0;
        }
        __syncthreads();
        for (int i = threadIdx.x; i < lim; i += 256) {
            int e = base + i;
            int r = row[e];
            int b = r >> SB;
            int pos = ofs[b] + atomicAdd(&cnt[b], 1);
            if (pos < (b + 1) * CAP)   // 10-sigma guard, never triggers
                eA[pos] = ((u64)__float_as_uint(w[e]) << 32)
                        | ((u64)(unsigned)(r & (BKN - 1)) << 24)
                        | (u64)(unsigned)col[e];
        }
        __syncthreads();
    }
}

// ------- phase 2: single-pass LDS fine sort (in-place) + start/end + dis -----

__global__ __launch_bounds__(256) void k_fine(const int* __restrict__ bcur,
                                              u64* __restrict__ eA,
                                              int* __restrict__ start,
                                              int* __restrict__ end,
                                              float* __restrict__ dis, int N) {
    __shared__ u64 lrec[CAP];                 // 37888 B
    __shared__ int ncnt[256];
    __shared__ float degs[256];
    __shared__ int sa[256], sb2[256];
    int b = blockIdx.x;
    int s = b * CAP;
    int cnt = bcur[b] - s;
    if (cnt > CAP) cnt = CAP;
    int t = threadIdx.x;
    ncnt[t] = 0;
    degs[t] = 0.f;
    __syncthreads();
    // load + count in one pass
    for (int i = t; i < cnt; i += 256) {
        u64 p = eA[s + i];
        lrec[i] = p;
        int rl = (int)((p >> 24) & 0xFF);
        atomicAdd(&ncnt[rl], 1);
        atomicAdd(&degs[rl], __uint_as_float((unsigned)(p >> 32)));
    }
    __syncthreads();
    int c = ncnt[t];
    sa[t] = c;
    __syncthreads();
    int *src = sa, *dst = sb2;
    for (int o = 1; o < 256; o <<= 1) {
        int v = src[t];
        if (t >= o) v += src[t - o];
        dst[t] = v;
        __syncthreads();
        int* tm = src; src = dst; dst = tm;
    }
    int excl = src[t] - c;
    int node = (b << SB) + t;
    if (node < N) {
        start[node] = s + excl;
        end[node]   = s + excl + c;
        float d = FILL + degs[t];
        dis[node] = (d > 0.f) ? rsqrtf(fmaxf(d, 1e-12f)) : 0.f;
    }
    ncnt[t] = excl;          // reuse as bucket-relative cursor
    __syncthreads();
    for (int i = t; i < cnt; i += 256) {
        u64 p = lrec[i];
        int rl = (int)((p >> 24) & 0xFF);
        int pos = atomicAdd(&ncnt[rl], 1);
        eA[s + pos] = p & 0xFFFFFFFF00FFFFFFULL;
    }
}

// ---------------- h2b = bf16( dis[r] * (x @ kernel) ) ----------------

__global__ __launch_bounds__(256) void k_gemm(const float* __restrict__ x,
                                              const float* __restrict__ kern,
                                              const float* __restrict__ dis,
                                              unsigned* __restrict__ h2b, int n) {
    __shared__ __align__(16) float ks[64 * 64];
    __shared__ __align__(16) float xs[64 * 68];
    int t = threadIdx.x;

    const float4* k4g = (const float4*)kern;
    float4* ks4 = (float4*)ks;
    #pragma unroll
    for (int i = 0; i < 4; ++i) ks4[t + i * 256] = k4g[t + i * 256];

    int r0 = blockIdx.x * 64;
    #pragma unroll
    for (int i = 0; i < 4; ++i) {
        int idx = t + i * 256;
        int rr = idx >> 4;
        int c4 = (idx & 15) << 2;
        int gr = r0 + rr;
        float4 v = make_float4(0.f, 0.f, 0.f, 0.f);
        if (gr < n) v = *(const float4*)(x + (size_t)gr * 64 + c4);
        *(float4*)(xs + rr * 68 + c4) = v;
    }
    __syncthreads();

    int rg = t >> 4;
    int ug = t & 15;
    float4 acc[4];
    #pragma unroll
    for (int r = 0; r < 4; ++r) acc[r] = make_float4(0.f, 0.f, 0.f, 0.f);

    #pragma unroll 2
    for (int kk = 0; kk < 16; ++kk) {
        float4 wv0 = *(const float4*)(ks + (kk * 4 + 0) * 64 + ug * 4);
        float4 wv1 = *(const float4*)(ks + (kk * 4 + 1) * 64 + ug * 4);
        float4 wv2 = *(const float4*)(ks + (kk * 4 + 2) * 64 + ug * 4);
        float4 wv3 = *(const float4*)(ks + (kk * 4 + 3) * 64 + ug * 4);
        #pragma unroll
        for (int r = 0; r < 4; ++r) {
            float4 xv = *(const float4*)(xs + (rg * 4 + r) * 68 + kk * 4);
            acc[r].x = fmaf(xv.x, wv0.x, acc[r].x);
            acc[r].y = fmaf(xv.x, wv0.y, acc[r].y);
            acc[r].z = fmaf(xv.x, wv0.z, acc[r].z);
            acc[r].w = fmaf(xv.x, wv0.w, acc[r].w);
            acc[r].x = fmaf(xv.y, wv1.x, acc[r].x);
            acc[r].y = fmaf(xv.y, wv1.y, acc[r].y);
            acc[r].z = fmaf(xv.y, wv1.z, acc[r].z);
            acc[r].w = fmaf(xv.y, wv1.w, acc[r].w);
            acc[r].x = fmaf(xv.z, wv2.x, acc[r].x);
            acc[r].y = fmaf(xv.z, wv2.y, acc[r].y);
            acc[r].z = fmaf(xv.z, wv2.z, acc[r].z);
            acc[r].w = fmaf(xv.z, wv2.w, acc[r].w);
            acc[r].x = fmaf(xv.w, wv3.x, acc[r].x);
            acc[r].y = fmaf(xv.w, wv3.y, acc[r].y);
            acc[r].z = fmaf(xv.w, wv3.z, acc[r].z);
            acc[r].w = fmaf(xv.w, wv3.w, acc[r].w);
        }
    }

    #pragma unroll
    for (int r = 0; r < 4; ++r) {
        int gr = r0 + rg * 4 + r;
        if (gr < n) {
            float d = dis[gr];
            uint2 uu;
            uu.x = pack2(d * acc[r].x, d * acc[r].y);
            uu.y = pack2(d * acc[r].z, d * acc[r].w);
            *(uint2*)(h2b + (size_t)gr * 32 + ug * 2) = uu;
        }
    }
}

// -------- phase 4: pull, wave per node, 4 edge slots x 16 lanes x uint2 ------

__global__ __launch_bounds__(256) void k_pull(const int* __restrict__ start,
                                              const int* __restrict__ end,
                                              const u64* __restrict__ edges,
                                              const unsigned* __restrict__ h2b,
                                              const float* __restrict__ dis,
                                              const float* __restrict__ bias,
                                              float* __restrict__ out, int N) {
    int node = (blockIdx.x << 2) + (threadIdx.x >> 6);
    int lane = threadIdx.x & 63;
    if (node >= N) return;
    int s = start[node], e1 = end[node];
    int slot = lane >> 4;   // 0..3: which edge of each quad
    int uw   = lane & 15;   // uint2 word pair -> units 4uw..4uw+3
    float a0 = 0.f, a1 = 0.f, a2 = 0.f, a3 = 0.f;
    #pragma unroll 2
    for (int j = s + slot; j < e1; j += 4) {
        u64 p = edges[j];                 // broadcast load (same addr per 16 lanes)
        unsigned c = (unsigned)p & 0xFFFFFFu;
        float v = __uint_as_float((unsigned)(p >> 32));
        uint2 g = *(const uint2*)(h2b + ((size_t)c << 5) + (uw << 1));
        a0 = fmaf(v, unlo(g.x), a0);
        a1 = fmaf(v, unhi(g.x), a1);
        a2 = fmaf(v, unlo(g.y), a2);
        a3 = fmaf(v, unhi(g.y), a3);
    }
    a0 += __shfl_xor(a0, 16); a0 += __shfl_xor(a0, 32);
    a1 += __shfl_xor(a1, 16); a1 += __shfl_xor(a1, 32);
    a2 += __shfl_xor(a2, 16); a2 += __shfl_xor(a2, 32);
    a3 += __shfl_xor(a3, 16); a3 += __shfl_xor(a3, 32);
    if (slot == 0) {
        float di = dis[node];
        uint2 gs = *(const uint2*)(h2b + ((size_t)node << 5) + (uw << 1));
        float4 bv = *(const float4*)(bias + 4 * uw);
        float4 o;
        o.x = di * (a0 + FILL * unlo(gs.x)) + bv.x;
        o.y = di * (a1 + FILL * unhi(gs.x)) + bv.y;
        o.z = di * (a2 + FILL * unlo(gs.y)) + bv.z;
        o.w = di * (a3 + FILL * unhi(gs.y)) + bv.w;
        *(float4*)(out + ((size_t)node << 6) + 4 * uw) = o;
    }
}

// ---------------- fallback (atomic scatter) ----------------

__global__ void k_fb_deg_init(float* __restrict__ deg, int n) {
    int i = blockIdx.x * blockDim.x + threadIdx.x;
    if (i < n) deg[i] = FILL;
}
__global__ void k_fb_deg_edges(const int* __restrict__ row, const float* __restrict__ w,
                               float* __restrict__ deg, int E) {
    int e = blockIdx.x * blockDim.x + threadIdx.x;
    if (e < E) atomicAdd(&deg[row[e]], w[e]);
}
__global__ void k_fb_dis(const float* __restrict__ deg, float* __restrict__ dis, int n) {
    int i = blockIdx.x * blockDim.x + threadIdx.x;
    if (i < n) {
        float d = deg[i];
        dis[i] = (d > 0.f) ? rsqrtf(fmaxf(d, 1e-12f)) : 0.f;
    }
}
__global__ void k_fb_outinit(const unsigned* __restrict__ h2b, const float* __restrict__ dis,
                             const float* __restrict__ bias, float* __restrict__ out, int n) {
    int t = blockIdx.x * blockDim.x + threadIdx.x;
    if (t < n * 64) {
        int i = t >> 6, u = t & 63;
        unsigned g = h2b[(size_t)i * 32 + (u >> 1)];
        float hv = (u & 1) ? unhi(g) : unlo(g);
        out[t] = FILL * dis[i] * hv + bias[u];
    }
}
__global__ __launch_bounds__(256) void k_fb_scatter(const int* __restrict__ row,
                                                    const int* __restrict__ col,
                                                    const float* __restrict__ w,
                                                    const float* __restrict__ dis,
                                                    const unsigned* __restrict__ h2b,
                                                    float* __restrict__ out, int E) {
    long long t = (long long)blockIdx.x * blockDim.x + threadIdx.x;
    int e = (int)(t >> 4);
    int j = (int)(t & 15);
    if (e < E) {
        int r = row[e], c = col[e];
        float nw = dis[r] * w[e];
        uint2 g2 = *(const uint2*)(h2b + (size_t)c * 32 + 2 * j);
        float* op = out + (long long)r * 64 + j * 4;
        atomicAdd(op + 0, unlo(g2.x) * nw);
        atomicAdd(op + 1, unhi(g2.x) * nw);
        atomicAdd(op + 2, unlo(g2.y) * nw);
        atomicAdd(op + 3, unhi(g2.y) * nw);
    }
}

// ---------------- launch ----------------

extern "C" void kernel_launch(void* const* d_in, const int* in_sizes, int n_in,
                              void* d_out, int out_size, void* d_ws, size_t ws_size,
                              hipStream_t stream) {
    const float* x    = (const float*)d_in[0];
    const int*   ei   = (const int*)d_in[1];
    const float* ew   = (const float*)d_in[2];
    const float* kern = (const float*)d_in[3];
    const float* bias = (const float*)d_in[4];
    float* out = (float*)d_out;

    int N = in_sizes[0] / 64;
    int E = in_sizes[1] / 2;
    const int* row = ei;
    const int* col = ei + E;

    const int B = 256;
    int NB = (N + BKN - 1) >> SB;

    // capacity check: CAP must exceed mean bucket fill by >= 8 sigma
    double meanB = (double)E / NB;
    bool capOK = (double)CAP >= meanB + 8.0 * sqrt(meanB) + 32.0;

    size_t need = (size_t)NB * CAP * 8        // eA (fixed-capacity regions)
                + (size_t)N * 128             // h2b (bf16 pairs)
                + (size_t)N * 4               // dis
                + (size_t)N * 4               // start
                + (size_t)N * 4               // end
                + (size_t)NB * 4;             // bcur

    if (ws_size >= need && capOK && NB <= 512 && N <= (1 << 24)) {
        char* p = (char*)d_ws;
        u64*      eA    = (u64*)p;         p += (size_t)NB * CAP * 8;
        unsigned* h2b   = (unsigned*)p;    p += (size_t)N * 128;
        float*    dis   = (float*)p;       p += (size_t)N * 4;
        int*      start = (int*)p;         p += (size_t)N * 4;
        int*      end   = (int*)p;         p += (size_t)N * 4;
        int*      bcur  = (int*)p;

        int nt = (E + TILE - 1) >> TSH;
        k_init<<<(NB + B - 1) / B, B, 0, stream>>>(bcur, NB);
        k_bscatter<<<nt, B, 0, stream>>>(row, col, ew, bcur, eA, E, NB);
        k_fine<<<NB, B, 0, stream>>>(bcur, eA, start, end, dis, N);
        k_gemm<<<(N + 63) / 64, B, 0, stream>>>(x, kern, dis, h2b, N);
        k_pull<<<(N + 3) / 4, B, 0, stream>>>(start, end, eA, h2b, dis, bias, out, N);
    } else {
        char* p = (char*)d_ws;
        unsigned* h2b = (unsigned*)p;  p += (size_t)N * 128;
        float*    deg = (float*)p;     p += (size_t)N * 4;
        float*    dis = (float*)p;

        k_fb_deg_init<<<(N + B - 1) / B, B, 0, stream>>>(deg, N);
        k_fb_deg_edges<<<(E + B - 1) / B, B, 0, stream>>>(row, ew, deg, E);
        k_fb_dis<<<(N + B - 1) / B, B, 0, stream>>>(deg, dis, N);
        k_gemm<<<(N + 63) / 64, B, 0, stream>>>(x, kern, dis, h2b, N);
        k_fb_outinit<<<((long long)N * 64 + B - 1) / B, B, 0, stream>>>(h2b, dis, bias, out, N);
        long long st = (long long)E * 16;
        k_fb_scatter<<<(st + B - 1) / B, B, 0, stream>>>(row, col, ew, dis, h2b, out, E);
    }
}